// Round 5
// baseline (128.005 us; speedup 1.0000x reference)
//
#include <hip/hip_runtime.h>
#include <hip/hip_bf16.h>

// Ensemble Q-network, fused, transposed ([features x batch]).
//   h1^T = relu(W1^T x^T + b1);  acc = W2^T h1^T + b2;  out = W3 . relu(acc)  in-register.
// R2: BT=64, 4 waves/block, 4 blocks/CU -> fused 50.4us.
// R3: FAILED deep pipeline (spill, 590MB scratch). R4: in-kernel x-stage, neutral.
// R5: 16x16x32 -> 32x32x16 MFMA everywhere. Counters show MfmaUtil 39 + VALUBusy 49
//     ~= 88% issue-occupied at the 16-waves/CU register cap -> issue-bound. 32x32x16
//     halves MFMA instruction count (144->72/wave) and cuts matrix-pipe cycles ~17%
//     (4096 vs 3413 FLOP/cyc), same register budget (acc = 2x2 f32x16 = 64 AGPR).
//     Fragment maps: A row=lane&31, k=(lane>>5)*8+j; C/D col=lane&31,
//     row=(r&3)+8*(r>>2)+4*(lane>>5). b1 folded into w1p spare k=23 slot with
//     xs[k=23]=1.0 (layer-1 acc init = 0, no b1 loads). Layer-3 loses one shuffle.

typedef __attribute__((ext_vector_type(8))) short bf16x8;    // 8 bf16 (4 VGPRs)
typedef __attribute__((ext_vector_type(16))) float f32x16;   // 32x32 MFMA C/D

#define B_TOTAL 32768
#define NQ 10
#define HDIM 256
#define BT 64

#define W1P_ELEMS (NQ * 2 * 8 * 64 * 8)      // [n][ks2][mtile8][lane64][j8]
#define W2P_ELEMS (NQ * 8 * 2 * 8 * 64 * 8)  // [n][kt8][ks2][mtile8][lane64][j8]

__device__ __forceinline__ unsigned short f2bf(float f) {
  unsigned int u = __float_as_uint(f);
  u = u + 0x7FFFu + ((u >> 16) & 1u);
  return (unsigned short)(u >> 16);
}

__device__ __forceinline__ unsigned int pk2bf(float a, float b) {
  union { __hip_bfloat162 h; unsigned int u; } cv;
  cv.h = __float22bfloat162_rn(make_float2(a, b));
  return cv.u;
}

// ---- pack dispatch: weights only (W1^T+b1, W2^T -> 32x32 MFMA A-frag order) ----
__global__ void pack_w_kernel(const float* __restrict__ W1,
                              const float* __restrict__ b1,
                              const float* __restrict__ W2,
                              unsigned short* __restrict__ w1p,
                              unsigned short* __restrict__ w2p) {
  int t = blockIdx.x * 256 + threadIdx.x;   // 360 * 256 = 92160 exactly
  const int NW1 = NQ * 2 * 8 * 64;          // 10240
  if (t < NW1) {
    int u = t;
    int lane = u & 63, mtile = (u >> 6) & 7, ks = (u >> 9) & 1, n = u >> 10;
    int outc = mtile * 32 + (lane & 31);
    int kbase = ks * 16 + (lane >> 5) * 8;
    unsigned short v[8];
#pragma unroll
    for (int j = 0; j < 8; j++) {
      int k = kbase + j;
      v[j] = (k < 23) ? f2bf(W1[(n * 23 + k) * 256 + outc])
           : (k == 23) ? f2bf(b1[n * 256 + outc]) : (unsigned short)0;
    }
    *(uint4*)&w1p[(size_t)u * 8] = *(const uint4*)v;
  } else {
    int u = t - NW1;                        // < 81920
    int lane = u & 63, mtile = (u >> 6) & 7, ks = (u >> 9) & 1, kt = (u >> 10) & 7, n = u >> 13;
    int outc = mtile * 32 + (lane & 31);
    int kbase = kt * 32 + ks * 16 + (lane >> 5) * 8;
    unsigned short v[8];
#pragma unroll
    for (int j = 0; j < 8; j++)
      v[j] = f2bf(W2[((size_t)(n * 256 + kbase + j)) * 256 + outc]);
    *(uint4*)&w2p[(size_t)u * 8] = *(const uint4*)v;
  }
}

// ---- fused MLP: 5120 blocks x 256 threads (4 waves), 4 blocks/CU ----
// wave w: channels [w*64, w*64+64) as 2 x 32-row tiles; cols = block's 64 rows as 2 x 32
__global__ __launch_bounds__(256, 4) void fused_ensemble_kernel(
    const float* __restrict__ state,
    const float* __restrict__ action,
    const unsigned short* __restrict__ w1p,
    const unsigned short* __restrict__ w2p,
    const float* __restrict__ b2,
    const float* __restrict__ W3,
    const float* __restrict__ b3,
    float* __restrict__ out) {
  __shared__ __align__(16) unsigned short hs[32 * 64 * 8];  // 32 KB, [ch/8][col][8]
  __shared__ __align__(16) unsigned short xs[4 * 64 * 8];   // 4 KB, [k/8][col][8]
  __shared__ float red[4 * 64];                             // 1 KB cross-wave reduce

  const int tid = threadIdx.x;
  const int lane = tid & 63;
  const int w = tid >> 6;       // 0..3: channels [w*64, w*64+64)
  const int c = lane & 31;      // col within 32-tile
  const int hi = lane >> 5;     // k-half / row-offset bit

  const int n = blockIdx.x >> 9;            // 512 tiles per net
  const int row0 = (blockIdx.x & 511) * BT;

  // acc[mt][nt]: ch = w*64 + mt*32 + (r&3)+8*(r>>2)+4*hi, col = nt*32 + c
  f32x16 acc[2][2];

  // ---- layer-1 A-frags issued first (hide under xs staging + barrier) ----
  bf16x8 af1[2][2];
#pragma unroll
  for (int ks = 0; ks < 2; ks++)
#pragma unroll
    for (int mt = 0; mt < 2; mt++)
      af1[ks][mt] = *(const bf16x8*)(w1p + ((((size_t)n * 2 + ks) * 8 + w * 2 + mt) * 64 + lane) * 8);

  // ---- stage x -> xs[k/8][col][8] (f32 -> bf16; k=23 slot = 1.0 for bias) ----
  {
    int r = tid >> 2, seg = tid & 3;        // 64 rows x 4 segs of 8 k
    int row = row0 + r;
    unsigned short v[8];
    if (seg < 2) {
      const float* sp = state + (size_t)row * 17 + seg * 8;
#pragma unroll
      for (int j = 0; j < 8; j++) v[j] = f2bf(sp[j]);
    } else if (seg == 2) {
      v[0] = f2bf(state[(size_t)row * 17 + 16]);
      const float* ap = action + (size_t)row * 6;
#pragma unroll
      for (int j = 0; j < 6; j++) v[1 + j] = f2bf(ap[j]);
      v[7] = 0x3F80;                        // bf16(1.0) -> bias lane (k=23)
    } else {
#pragma unroll
      for (int j = 0; j < 8; j++) v[j] = 0;
    }
    *(uint4*)&xs[((size_t)seg * 64 + r) * 8] = *(const uint4*)v;
  }
  __syncthreads();

  // ---- layer 1: K=32 as 2 x (32x32x16); bias rides k=23 ----
  {
    bf16x8 bfr[2][2];
#pragma unroll
    for (int ks = 0; ks < 2; ks++)
#pragma unroll
      for (int nt = 0; nt < 2; nt++)
        bfr[ks][nt] = *(const bf16x8*)&xs[(((size_t)ks * 2 + hi) * 64 + nt * 32 + c) * 8];
    const f32x16 zz = {0.f,0.f,0.f,0.f,0.f,0.f,0.f,0.f,0.f,0.f,0.f,0.f,0.f,0.f,0.f,0.f};
#pragma unroll
    for (int mt = 0; mt < 2; mt++)
#pragma unroll
      for (int nt = 0; nt < 2; nt++) acc[mt][nt] = zz;
    __builtin_amdgcn_s_setprio(1);
#pragma unroll
    for (int ks = 0; ks < 2; ks++)
#pragma unroll
      for (int nt = 0; nt < 2; nt++)
#pragma unroll
        for (int mt = 0; mt < 2; mt++)
          acc[mt][nt] = __builtin_amdgcn_mfma_f32_32x32x16_bf16(af1[ks][mt], bfr[ks][nt],
                                                                acc[mt][nt], 0, 0, 0);
    __builtin_amdgcn_s_setprio(0);
  }

  // ---- epilogue 1: relu -> h1 bf16 into hs[ch/8][col][8]; one b64 per reg-quad ----
#pragma unroll
  for (int mt = 0; mt < 2; mt++)
#pragma unroll
    for (int nt = 0; nt < 2; nt++) {
      f32x16 a = acc[mt][nt];
#pragma unroll
      for (int g = 0; g < 4; g++) {
        uint2 wv;
        wv.x = pk2bf(fmaxf(a[4 * g + 0], 0.f), fmaxf(a[4 * g + 1], 0.f));
        wv.y = pk2bf(fmaxf(a[4 * g + 2], 0.f), fmaxf(a[4 * g + 3], 0.f));
        // ch = w*64 + mt*32 + g*8 + hi*4 + (0..3) -> ch/8 = w*8+mt*4+g, j = hi*4+(0..3)
        *(uint2*)&hs[(((size_t)w * 8 + mt * 4 + g) * 64 + nt * 32 + c) * 8 + hi * 4] = wv;
      }
    }

  // ---- layer-2 first A-frags: issue BEFORE the barrier (hide under wait) ----
  const unsigned short* w2n = w2p + (size_t)n * 65536;
  bf16x8 acur[2][2], anxt[2][2];
#pragma unroll
  for (int ks = 0; ks < 2; ks++)
#pragma unroll
    for (int mt = 0; mt < 2; mt++)
      acur[ks][mt] = *(const bf16x8*)(w2n + (((size_t)ks * 8 + w * 2 + mt) * 64 + lane) * 8);
  __syncthreads();

  // ---- layer 2: 8 K-steps of 32 (2 x 32x32x16 each); A 1-deep prefetch from L2 ----
  {
    float4 b2g[2][4];
#pragma unroll
    for (int mt = 0; mt < 2; mt++)
#pragma unroll
      for (int g = 0; g < 4; g++)
        b2g[mt][g] = *(const float4*)&b2[n * HDIM + w * 64 + mt * 32 + g * 8 + hi * 4];
#pragma unroll
    for (int mt = 0; mt < 2; mt++) {
      f32x16 bi;
#pragma unroll
      for (int g = 0; g < 4; g++) {
        bi[4 * g + 0] = b2g[mt][g].x;
        bi[4 * g + 1] = b2g[mt][g].y;
        bi[4 * g + 2] = b2g[mt][g].z;
        bi[4 * g + 3] = b2g[mt][g].w;
      }
      acc[mt][0] = bi;
      acc[mt][1] = bi;
    }
#pragma unroll
    for (int kt = 0; kt < 8; kt++) {
      if (kt < 7) {
#pragma unroll
        for (int ks = 0; ks < 2; ks++)
#pragma unroll
          for (int mt = 0; mt < 2; mt++)
            anxt[ks][mt] = *(const bf16x8*)(
                w2n + ((((size_t)(kt + 1) * 2 + ks) * 8 + w * 2 + mt) * 64 + lane) * 8);
      }
      bf16x8 bfr[2][2];
#pragma unroll
      for (int ks = 0; ks < 2; ks++)
#pragma unroll
        for (int nt = 0; nt < 2; nt++)
          bfr[ks][nt] = *(const bf16x8*)&hs[(((size_t)kt * 4 + ks * 2 + hi) * 64 + nt * 32 + c) * 8];
      __builtin_amdgcn_s_setprio(1);
#pragma unroll
      for (int ks = 0; ks < 2; ks++)
#pragma unroll
        for (int nt = 0; nt < 2; nt++)
#pragma unroll
          for (int mt = 0; mt < 2; mt++)
            acc[mt][nt] = __builtin_amdgcn_mfma_f32_32x32x16_bf16(acur[ks][mt], bfr[ks][nt],
                                                                  acc[mt][nt], 0, 0, 0);
      __builtin_amdgcn_s_setprio(0);
#pragma unroll
      for (int ks = 0; ks < 2; ks++)
#pragma unroll
        for (int mt = 0; mt < 2; mt++) acur[ks][mt] = anxt[ks][mt];
    }
  }

  // ---- layer 3 in-register: p[col] = sum_ch relu(acc_ch) * W3[ch]; reduce ----
  {
    float4 w3g[2][4];
#pragma unroll
    for (int mt = 0; mt < 2; mt++)
#pragma unroll
      for (int g = 0; g < 4; g++)
        w3g[mt][g] = *(const float4*)&W3[n * HDIM + w * 64 + mt * 32 + g * 8 + hi * 4];
    float p[2];
#pragma unroll
    for (int nt = 0; nt < 2; nt++) {
      float s = 0.f;
#pragma unroll
      for (int mt = 0; mt < 2; mt++) {
        f32x16 a = acc[mt][nt];
#pragma unroll
        for (int g = 0; g < 4; g++) {
          float4 wv = w3g[mt][g];
          s = fmaf(fmaxf(a[4 * g + 0], 0.f), wv.x, s);
          s = fmaf(fmaxf(a[4 * g + 1], 0.f), wv.y, s);
          s = fmaf(fmaxf(a[4 * g + 2], 0.f), wv.z, s);
          s = fmaf(fmaxf(a[4 * g + 3], 0.f), wv.w, s);
        }
      }
      s += __shfl_xor(s, 32, 64);   // combine hi halves (channels)
      p[nt] = s;
    }
    if (hi == 0) {
      red[w * 64 + c] = p[0];
      red[w * 64 + 32 + c] = p[1];
    }
    __syncthreads();
    if (tid < BT) {
      float s = b3[n];
#pragma unroll
      for (int cw = 0; cw < 4; cw++) s += red[cw * 64 + tid];
      out[(size_t)n * B_TOTAL + row0 + tid] = s;
    }
  }
}

extern "C" void kernel_launch(void* const* d_in, const int* in_sizes, int n_in,
                              void* d_out, int out_size, void* d_ws, size_t ws_size,
                              hipStream_t stream) {
  const float* state  = (const float*)d_in[0];
  const float* action = (const float*)d_in[1];
  const float* W1 = (const float*)d_in[2];
  const float* b1 = (const float*)d_in[3];
  const float* W2 = (const float*)d_in[4];
  const float* b2 = (const float*)d_in[5];
  const float* W3 = (const float*)d_in[6];
  const float* b3 = (const float*)d_in[7];
  float* out = (float*)d_out;

  unsigned short* w1p = (unsigned short*)d_ws;                                    // 163,840 B
  unsigned short* w2p = (unsigned short*)((char*)d_ws + (size_t)W1P_ELEMS * 2);   // 1,310,720 B

  pack_w_kernel<<<360, 256, 0, stream>>>(W1, b1, W2, w1p, w2p);
  fused_ensemble_kernel<<<NQ * (B_TOTAL / BT), 256, 0, stream>>>(
      state, action, w1p, w2p, b2, W3, b3, out);
}

// Round 6
// 117.724 us; speedup vs baseline: 1.0873x; 1.0873x over previous
//
#include <hip/hip_runtime.h>
#include <hip/hip_bf16.h>

// Ensemble Q-network, fused, transposed ([features x batch]).
//   h1^T = relu(W1^T x^T [+b1 via k=23]);  acc = W2^T h1^T + b2;  out = W3 . relu(acc).
// R2 (best, fused 50.4us): BT=64, 4 waves/block, 4 blocks/CU, xp packed global,
//     layer-1 B-frags direct from xp, 1-deep A prefetch (fits 64 VGPR).
// R3 FAILED: deep pipeline -> spill (590MB scratch). R4: in-kernel x-stage -> fused
//     +1.4us (10x-redundant staging). R5 FAILED: 32x32x16 -> thinner compute phase
//     broke L2 latency cover (64.5us). All reverted; base = R2.
// R6: VALU surgery on R2 (MfmaUtil 40 + VALUBusy 46, VALU co-limiting):
//     (a) b1 folded into w1p k=23 slot, xp[k=23]=1.0 -> no b1 loads, acc1 zero-init.
//     (b) packed f32: relu via __builtin_elementwise_max (v_pk_max_f32), layer-3
//         dot via float2 mul-add (v_pk_fma_f32) -> ~95 fewer VALU instrs/thread.
//     (c) afb[kt&1] ping-pong (no acur<-anxt copies; same 32-VGPR live set).

typedef __attribute__((ext_vector_type(8))) short bf16x8;   // 8 bf16 (4 VGPRs)
typedef __attribute__((ext_vector_type(4))) float f32x4;    // MFMA C/D
typedef __attribute__((ext_vector_type(2))) float f32x2;

#define B_TOTAL 32768
#define NQ 10
#define HDIM 256
#define BT 64

#define XP_ELEMS  (B_TOTAL * 32)            // bf16 x, k-padded to 32 (k=23 slot = 1.0)
#define W1P_ELEMS (NQ * 16 * 64 * 8)        // [n][mtile16][lane64][j8]
#define W2P_ELEMS (NQ * 8 * 16 * 64 * 8)    // [n][kt8][mtile16][lane64][j8]

__device__ __forceinline__ unsigned short f2bf(float f) {
  unsigned int u = __float_as_uint(f);
  u = u + 0x7FFFu + ((u >> 16) & 1u);
  return (unsigned short)(u >> 16);
}

__device__ __forceinline__ unsigned int pk2bf(float a, float b) {
  union { __hip_bfloat162 h; unsigned int u; } cv;
  cv.h = __float22bfloat162_rn(make_float2(a, b));
  return cv.u;
}

// ---- single pack dispatch: x, W1^T(+b1), W2^T ----
__global__ void pack_all_kernel(const float* __restrict__ state,
                                const float* __restrict__ action,
                                const float* __restrict__ W1,
                                const float* __restrict__ b1,
                                const float* __restrict__ W2,
                                unsigned short* __restrict__ xp,
                                unsigned short* __restrict__ w1p,
                                unsigned short* __restrict__ w2p) {
  int t = blockIdx.x * 256 + threadIdx.x;   // 872 * 256 = 223232 exactly
  const int NX  = B_TOTAL * 4;              // 131072 uint4 chunks of xp
  const int NW1 = NQ * 16 * 64;             // 10240
  if (t < NX) {
    int b = t >> 2, seg = t & 3;
    unsigned short v[8];
    if (seg < 2) {
      const float* sp = state + (size_t)b * 17 + seg * 8;
#pragma unroll
      for (int j = 0; j < 8; j++) v[j] = f2bf(sp[j]);
    } else if (seg == 2) {
      v[0] = f2bf(state[(size_t)b * 17 + 16]);
#pragma unroll
      for (int j = 0; j < 6; j++) v[1 + j] = f2bf(action[(size_t)b * 6 + j]);
      v[7] = 0x3F80;                        // bf16(1.0): bias lane (k=23)
    } else {
#pragma unroll
      for (int j = 0; j < 8; j++) v[j] = 0;
    }
    *(uint4*)&xp[(size_t)t * 8] = *(const uint4*)v;
  } else if (t < NX + NW1) {
    int u = t - NX;
    int lane = u & 63, mt = (u >> 6) & 15, n = u >> 10;
    int m = lane & 15, q = lane >> 4;
    int outc = mt * 16 + m;
    unsigned short v[8];
#pragma unroll
    for (int j = 0; j < 8; j++) {
      int k = q * 8 + j;
      v[j] = (k < 23) ? f2bf(W1[(n * 23 + k) * 256 + outc])
           : (k == 23) ? f2bf(b1[n * 256 + outc]) : (unsigned short)0;
    }
    *(uint4*)&w1p[(size_t)u * 8] = *(const uint4*)v;
  } else {
    int u = t - NX - NW1;                   // < 81920
    int lane = u & 63, mt = (u >> 6) & 15, kt = (u >> 10) & 7, n = u >> 13;
    int m = lane & 15, q = lane >> 4;
    int outc = mt * 16 + m;
    unsigned short v[8];
#pragma unroll
    for (int j = 0; j < 8; j++) {
      int h = kt * 32 + q * 8 + j;
      v[j] = f2bf(W2[((size_t)(n * 256 + h)) * 256 + outc]);
    }
    *(uint4*)&w2p[(size_t)u * 8] = *(const uint4*)v;
  }
}

// ---- fused MLP: 5120 blocks x 256 threads (4 waves), 4 blocks/CU ----
// wave w: channels [w*64, w*64+64); all waves share the block's 64 batch cols
__global__ __launch_bounds__(256, 4) void fused_ensemble_kernel(
    const unsigned short* __restrict__ xp,
    const unsigned short* __restrict__ w1p,
    const unsigned short* __restrict__ w2p,
    const float* __restrict__ b2,
    const float* __restrict__ W3,
    const float* __restrict__ b3,
    float* __restrict__ out) {
  __shared__ __align__(16) unsigned short hs[32 * BT * 8];  // 32 KB, [ch/8][col][8]
  __shared__ float red[4 * 64];                             // 1 KB cross-wave reduce

  const int tid = threadIdx.x;
  const int lane = tid & 63;
  const int w = tid >> 6;       // 0..3: channels [w*64, w*64+64)
  const int m = lane & 15;
  const int q = lane >> 4;

  const int n = blockIdx.x >> 9;            // 512 tiles per net
  const int row0 = (blockIdx.x & 511) * BT;

  f32x4 acc[4][4];   // [mt][nt]: ch = w*64 + mt*16 + q*4 + r, col = nt*16 + m

  // ---- layer 1: single K-step (K=32; k=23 carries the bias via xp=1.0) ----
  {
    bf16x8 af1[4], bfr[4];
#pragma unroll
    for (int nt = 0; nt < 4; nt++) {
      int col = row0 + nt * 16 + m;         // global batch row
      bfr[nt] = *(const bf16x8*)(xp + (size_t)col * 32 + q * 8);
    }
#pragma unroll
    for (int mt = 0; mt < 4; mt++)
      af1[mt] = *(const bf16x8*)(w1p + (((size_t)n * 16 + w * 4 + mt) * 64 + lane) * 8);
#pragma unroll
    for (int mt = 0; mt < 4; mt++)
#pragma unroll
      for (int nt = 0; nt < 4; nt++) acc[mt][nt] = (f32x4)0.0f;
    __builtin_amdgcn_s_setprio(1);
#pragma unroll
    for (int nt = 0; nt < 4; nt++)
#pragma unroll
      for (int mt = 0; mt < 4; mt++)
        acc[mt][nt] = __builtin_amdgcn_mfma_f32_16x16x32_bf16(af1[mt], bfr[nt], acc[mt][nt], 0, 0, 0);
    __builtin_amdgcn_s_setprio(0);
  }

  // ---- epilogue 1: relu (v_pk_max) -> h1 bf16 frag-chunk layout ----
#pragma unroll
  for (int mt = 0; mt < 4; mt++) {
    int kq = w * 8 + mt * 2 + (q >> 1);
    int joff = (q & 1) * 4;
#pragma unroll
    for (int nt = 0; nt < 4; nt++) {
      int col = nt * 16 + m;
      f32x4 a = __builtin_elementwise_max(acc[mt][nt], (f32x4)0.0f);
      uint2 wv;
      wv.x = pk2bf(a.x, a.y);
      wv.y = pk2bf(a.z, a.w);
      *(uint2*)&hs[((size_t)kq * BT + col) * 8 + joff] = wv;
    }
  }

  // ---- layer-2 first A-frags + bias: issue BEFORE the barrier ----
  const unsigned short* w2n = w2p + (size_t)n * (8 * 16 * 64 * 8);
  bf16x8 afb[2][4];                         // ping-pong A prefetch (no copies)
#pragma unroll
  for (int mt = 0; mt < 4; mt++)
    afb[0][mt] = *(const bf16x8*)(w2n + (((size_t)w * 4 + mt) * 64 + lane) * 8);
  f32x4 b2v[4];
#pragma unroll
  for (int mt = 0; mt < 4; mt++)
    b2v[mt] = *(const f32x4*)&b2[n * HDIM + (w * 4 + mt) * 16 + q * 4];
  __syncthreads();

  // ---- layer 2: 8 K-steps, A-frags streamed from L2 with 1-deep prefetch ----
  {
#pragma unroll
    for (int mt = 0; mt < 4; mt++)
#pragma unroll
      for (int nt = 0; nt < 4; nt++) acc[mt][nt] = b2v[mt];
#pragma unroll
    for (int kt = 0; kt < 8; kt++) {
      if (kt < 7) {
#pragma unroll
        for (int mt = 0; mt < 4; mt++)
          afb[(kt + 1) & 1][mt] =
              *(const bf16x8*)(w2n + (((size_t)(kt + 1) * 16 + w * 4 + mt) * 64 + lane) * 8);
      }
      bf16x8 bfr[4];
#pragma unroll
      for (int nt = 0; nt < 4; nt++)
        bfr[nt] = *(const bf16x8*)&hs[(((size_t)kt * 4 + q) * BT + nt * 16 + m) * 8];
      __builtin_amdgcn_s_setprio(1);
#pragma unroll
      for (int nt = 0; nt < 4; nt++)
#pragma unroll
        for (int mt = 0; mt < 4; mt++)
          acc[mt][nt] = __builtin_amdgcn_mfma_f32_16x16x32_bf16(afb[kt & 1][mt], bfr[nt],
                                                               acc[mt][nt], 0, 0, 0);
      __builtin_amdgcn_s_setprio(0);
    }
  }

  // ---- layer 3 in-register: p[col] = sum_ch relu(acc_ch) * W3[ch]; reduce ----
  {
    f32x4 w3v[4];
#pragma unroll
    for (int mt = 0; mt < 4; mt++)
      w3v[mt] = *(const f32x4*)&W3[n * HDIM + (w * 4 + mt) * 16 + q * 4];
    float p[4];
#pragma unroll
    for (int nt = 0; nt < 4; nt++) {
      f32x2 s2 = (f32x2)0.0f;
#pragma unroll
      for (int mt = 0; mt < 4; mt++) {
        f32x4 a = __builtin_elementwise_max(acc[mt][nt], (f32x4)0.0f);
        s2 += a.lo * w3v[mt].lo;            // v_pk_fma_f32
        s2 += a.hi * w3v[mt].hi;
      }
      float s = s2.x + s2.y;
      s += __shfl_xor(s, 16, 64);   // reduce q within wave (channels)
      s += __shfl_xor(s, 32, 64);
      p[nt] = s;
    }
    if (q == 0) {
#pragma unroll
      for (int nt = 0; nt < 4; nt++) red[w * 64 + nt * 16 + m] = p[nt];
    }
    __syncthreads();
    if (tid < BT) {
      float s = b3[n];
#pragma unroll
      for (int c = 0; c < 4; c++) s += red[c * 64 + tid];
      out[(size_t)n * B_TOTAL + row0 + tid] = s;
    }
  }
}

extern "C" void kernel_launch(void* const* d_in, const int* in_sizes, int n_in,
                              void* d_out, int out_size, void* d_ws, size_t ws_size,
                              hipStream_t stream) {
  const float* state  = (const float*)d_in[0];
  const float* action = (const float*)d_in[1];
  const float* W1 = (const float*)d_in[2];
  const float* b1 = (const float*)d_in[3];
  const float* W2 = (const float*)d_in[4];
  const float* b2 = (const float*)d_in[5];
  const float* W3 = (const float*)d_in[6];
  const float* b3 = (const float*)d_in[7];
  float* out = (float*)d_out;

  unsigned short* xp  = (unsigned short*)d_ws;                                    // 2,097,152 B
  unsigned short* w1p = (unsigned short*)((char*)d_ws + (size_t)XP_ELEMS * 2);    //   163,840 B
  unsigned short* w2p = (unsigned short*)((char*)d_ws + (size_t)(XP_ELEMS + W1P_ELEMS) * 2); // 1,310,720 B

  pack_all_kernel<<<872, 256, 0, stream>>>(state, action, W1, b1, W2, xp, w1p, w2p);
  fused_ensemble_kernel<<<NQ * (B_TOTAL / BT), 256, 0, stream>>>(
      xp, w1p, w2p, b2, W3, b3, out);
}